// Round 1
// baseline (172.095 us; speedup 1.0000x reference)
//
#include <hip/hip_runtime.h>

#define NCLS 91
#define NHIST (3 * NCLS)      // cnt_in[91] | cnt_tg[91] | inter[91]
#define NBLK 2048
#define BS 256
#define NWAVE (BS / 64)

__global__ void miou_zero_ws(unsigned int* __restrict__ ws) {
    int i = threadIdx.x;
    if (i < NHIST) ws[i] = 0u;
}

__global__ __launch_bounds__(BS) void miou_hist(const float* __restrict__ inp,
                                                const int* __restrict__ tgt,
                                                unsigned int* __restrict__ ws,
                                                int n4) {
    // Per-wave private histograms: no inter-wave LDS atomic contention.
    __shared__ unsigned int h[NWAVE][NHIST];
    for (int i = threadIdx.x; i < NWAVE * NHIST; i += BS)
        ((unsigned int*)h)[i] = 0u;
    __syncthreads();

    const int wave = threadIdx.x >> 6;
    unsigned int* hw = h[wave];

    int tid = blockIdx.x * BS + threadIdx.x;
    int stride = gridDim.x * BS;
    const float4* in4 = (const float4*)inp;
    const int4* tg4 = (const int4*)tgt;

    for (int i = tid; i < n4; i += stride) {
        float4 fv = in4[i];
        int4 tv = tg4[i];
        int a0 = (int)fv.x, a1 = (int)fv.y, a2 = (int)fv.z, a3 = (int)fv.w;
        atomicAdd(&hw[a0], 1u);
        atomicAdd(&hw[a1], 1u);
        atomicAdd(&hw[a2], 1u);
        atomicAdd(&hw[a3], 1u);
        atomicAdd(&hw[NCLS + tv.x], 1u);
        atomicAdd(&hw[NCLS + tv.y], 1u);
        atomicAdd(&hw[NCLS + tv.z], 1u);
        atomicAdd(&hw[NCLS + tv.w], 1u);
        // matches are ~1/91 of lanes: branch mostly execz-skips
        if (a0 == tv.x) atomicAdd(&hw[2 * NCLS + a0], 1u);
        if (a1 == tv.y) atomicAdd(&hw[2 * NCLS + a1], 1u);
        if (a2 == tv.z) atomicAdd(&hw[2 * NCLS + a2], 1u);
        if (a3 == tv.w) atomicAdd(&hw[2 * NCLS + a3], 1u);
    }
    __syncthreads();

    // Fold wave copies and push to global once per bin per block.
    for (int i = threadIdx.x; i < NHIST; i += BS) {
        unsigned int v = 0u;
        #pragma unroll
        for (int w = 0; w < NWAVE; ++w) v += h[w][i];
        if (v) atomicAdd(&ws[i], v);
    }
}

__global__ void miou_finalize(const unsigned int* __restrict__ ws,
                              const int* __restrict__ smooth_p,
                              float* __restrict__ out) {
    int lane = threadIdx.x;  // 64 threads
    float s = (float)(*smooth_p);
    float acc = 0.f;
    for (int c = 1 + lane; c < NCLS; c += 64) {
        float ci = (float)ws[c];
        float ct = (float)ws[NCLS + c];
        float it = (float)ws[2 * NCLS + c];
        float un = ci + ct - it;
        acc += (it + s) / (un + s);
    }
    #pragma unroll
    for (int off = 32; off; off >>= 1) acc += __shfl_down(acc, off);
    if (lane == 0) out[0] = acc / (float)(NCLS - 1);
}

extern "C" void kernel_launch(void* const* d_in, const int* in_sizes, int n_in,
                              void* d_out, int out_size, void* d_ws, size_t ws_size,
                              hipStream_t stream) {
    const float* inp = (const float*)d_in[0];
    const int* tgt = (const int*)d_in[1];
    const int* smooth_p = (const int*)d_in[2];
    float* out = (float*)d_out;
    unsigned int* ws = (unsigned int*)d_ws;

    int n = in_sizes[0];      // 64*512*512 = 16,777,216 (divisible by 4)
    int n4 = n >> 2;

    miou_zero_ws<<<1, 512, 0, stream>>>(ws);
    miou_hist<<<NBLK, BS, 0, stream>>>(inp, tgt, ws, n4);
    miou_finalize<<<1, 64, 0, stream>>>(ws, smooth_p, out);
}